// Round 4
// baseline (790.920 us; speedup 1.0000x reference)
//
#include <hip/hip_runtime.h>

#define NUM_USERS 100000
#define NUM_ITEMS 50000
#define NNODES    150000
#define EMB       64
#define NEDGES    4800000
#define BATCH     4096
#define NSAMP     (3 * BATCH)   // sampled rows for layer 3
#define RP_ALLOC  150528        // 147*1024, covers NNODES+1 with unguarded writes
#define NCHUNK    147           // ceil(150016/1024)

typedef unsigned short u16;
typedef unsigned int   u32;
typedef unsigned long long u64;
typedef float f32x4 __attribute__((ext_vector_type(4)));
typedef int   i32x4 __attribute__((ext_vector_type(4)));

__device__ inline float bf2f(u16 u) { return __uint_as_float(((u32)u) << 16); }
__device__ inline u16 f2bf(float f) {                 // RNE
    u32 b = __float_as_uint(f);
    b += 0x7FFFu + ((b >> 16) & 1u);
    return (u16)(b >> 16);
}
__device__ inline u32 pack2(float a, float b) {
    return (u32)f2bf(a) | ((u32)f2bf(b) << 16);
}

// l0 init: concat(user_emb, item_emb) -> bf16 table. nt loads (read-once),
// cached stores (l0 is gathered immediately by spmm layer 1).
__global__ void init_kernel(const float* __restrict__ user_emb,
                            const float* __restrict__ item_emb,
                            u16* __restrict__ l0) {
    long i = (long)blockIdx.x * blockDim.x + threadIdx.x;   // float4 units
    const long n4 = (long)NNODES * EMB / 4;
    if (i >= n4) return;
    const long nu4 = (long)NUM_USERS * EMB / 4;
    f32x4 v;
    if (i < nu4) v = __builtin_nontemporal_load((const f32x4*)user_emb + i);
    else         v = __builtin_nontemporal_load((const f32x4*)item_emb + (i - nu4));
    ushort4 o;
    o.x = f2bf(v.x); o.y = f2bf(v.y); o.z = f2bf(v.z); o.w = f2bf(v.w);
    ((ushort4*)l0)[i] = o;
}

// ---------------- CSR build, direct 3-step (replaces 2-pass bucket sort) ---
// Edge order within a row is arbitrary (atomic race) -- summation order only,
// error ~1e-7 << 6.1e-5 tolerance.

// Step 1: row histogram. i32x4 loads (4 edges/thread), fire-and-forget atomics.
__global__ void hist_kernel(const int* __restrict__ rows, int* __restrict__ cnt) {
    long i = (long)blockIdx.x * blockDim.x + threadIdx.x;   // i32x4 units
    if (i >= NEDGES / 4) return;
    i32x4 r = __builtin_nontemporal_load((const i32x4*)rows + i);
    atomicAdd(&cnt[r.x], 1);
    atomicAdd(&cnt[r.y], 1);
    atomicAdd(&cnt[r.z], 1);
    atomicAdd(&cnt[r.w], 1);
}

// Step 2a: per-1024-chunk exclusive scan; chunk totals -> partials.
__global__ void __launch_bounds__(1024) chunkscan_kernel(const int* __restrict__ cnt,
                                                         int* __restrict__ rowPtr,
                                                         int* __restrict__ partials) {
    __shared__ int wsum[16];
    const int b   = blockIdx.x;
    const int tid = threadIdx.x;
    const int wid = tid >> 6, lane = tid & 63;
    const int i = b * 1024 + tid;
    int v = (i < NNODES + 1) ? cnt[i] : 0;   // cnt[NNODES..] zeroed by memset
    int x = v;
    #pragma unroll
    for (int d = 1; d < 64; d <<= 1) {
        int t = __shfl_up(x, d, 64);
        if (lane >= d) x += t;
    }
    if (lane == 63) wsum[wid] = x;
    __syncthreads();
    if (tid < 16) {
        int s = wsum[tid];
        #pragma unroll
        for (int d = 1; d < 16; d <<= 1) {
            int t = __shfl_up(s, d, 16);
            if (tid >= d) s += t;
        }
        wsum[tid] = s;                        // inclusive wave-total scan
    }
    __syncthreads();
    int woff = wid ? wsum[wid - 1] : 0;
    rowPtr[i] = x - v + woff;                 // chunk-local exclusive
    if (tid == 0) partials[b] = wsum[15];     // chunk total
}

// Step 2b: exclusive scan of 147 chunk totals (1 wave, in place).
__global__ void scanpart_kernel(int* __restrict__ partials) {
    int lane = threadIdx.x;
    int carry = 0;
    for (int cb = 0; cb < NCHUNK; cb += 64) {
        int i = cb + lane;
        int orig = (i < NCHUNK) ? partials[i] : 0;
        int x = orig;
        #pragma unroll
        for (int d = 1; d < 64; d <<= 1) {
            int t = __shfl_up(x, d, 64);
            if (lane >= d) x += t;
        }
        int total = __shfl(x, 63, 64);
        if (i < NCHUNK) partials[i] = x - orig + carry;
        carry += total;
    }
}

// Step 2c: add chunk offsets back.
__global__ void __launch_bounds__(1024) addback_kernel(int* __restrict__ rowPtr,
                                                       const int* __restrict__ partials) {
    rowPtr[blockIdx.x * 1024 + threadIdx.x] += partials[blockIdx.x];
}

// Step 3: scatter edges into CSR windows. Returning atomic allocates slot;
// ~2048 in-flight atomics/CU hide the latency.
__global__ void scatter_kernel(const int* __restrict__ rows,
                               const int* __restrict__ cols,
                               const float* __restrict__ vals,
                               const int* __restrict__ rowPtr,
                               int* __restrict__ fill,
                               int2* __restrict__ csr) {
    long e = (long)blockIdx.x * blockDim.x + threadIdx.x;
    if (e >= NEDGES) return;
    int r = __builtin_nontemporal_load(rows + e);
    int c = __builtin_nontemporal_load(cols + e);
    float v = __builtin_nontemporal_load(vals + e);
    int pos = rowPtr[r] + atomicAdd(&fill[r], 1);
    csr[pos] = make_int2(c, __float_as_int(v));
}

#define ACCX(V, X) { \
    a[0] += (V) * __uint_as_float((X).x << 16); \
    a[1] += (V) * __uint_as_float((X).x & 0xFFFF0000u); \
    a[2] += (V) * __uint_as_float((X).y << 16); \
    a[3] += (V) * __uint_as_float((X).y & 0xFFFF0000u); \
    a[4] += (V) * __uint_as_float((X).z << 16); \
    a[5] += (V) * __uint_as_float((X).z & 0xFFFF0000u); \
    a[6] += (V) * __uint_as_float((X).w << 16); \
    a[7] += (V) * __uint_as_float((X).w & 0xFFFF0000u); }

// --- SpMM: 8 lanes per row, each lane owns 8 bf16 dims (one uint4 gather).
// R0 form exactly: VGPR 44, no spill. spmm is L2-miss byte-rate-bound
// (~3.3 TB/s); deeper pipelining spills and loses (R1/R2 post-mortem).
__global__ void spmm_csr(const int* __restrict__ rowPtr, const int2* __restrict__ csr,
                         const u16* __restrict__ cur, u16* __restrict__ nxt) {
    int gtid = blockIdx.x * blockDim.x + threadIdx.x;
    int row = gtid >> 3;
    int t   = gtid & 7;
    if (row >= NNODES) return;
    int beg = rowPtr[row], end = rowPtr[row + 1];
    float a[8];
    #pragma unroll
    for (int i = 0; i < 8; ++i) a[i] = 0.f;

    int e = beg;
    for (; e + 7 < end; e += 8) {            // 8 outstanding gathers
        int2 p[8];
        #pragma unroll
        for (int j = 0; j < 8; ++j) p[j] = csr[e + j];
        uint4 x[8];
        #pragma unroll
        for (int j = 0; j < 8; ++j)
            x[j] = *(const uint4*)(cur + ((long)p[j].x << 6) + (t << 3));
        #pragma unroll
        for (int j = 0; j < 8; ++j) {
            float v = __int_as_float(p[j].y);
            ACCX(v, x[j]);
        }
    }
    for (; e < end; ++e) {
        int2 p = csr[e];
        float v = __int_as_float(p.y);
        uint4 x = *(const uint4*)(cur + ((long)p.x << 6) + (t << 3));
        ACCX(v, x);
    }

    uint4 o;
    o.x = pack2(a[0], a[1]);
    o.y = pack2(a[2], a[3]);
    o.z = pack2(a[4], a[5]);
    o.w = pack2(a[6], a[7]);
    *(uint4*)(nxt + ((long)row << 6) + (t << 3)) = o;
}

// Layer 3 only at sampled rows: slot s<B -> users[s]; s<2B -> pos; s<3B -> neg.
// Output fp32 [NSAMP][64].
__global__ void spmm_sampled(const int* __restrict__ users,
                             const int* __restrict__ pos_items,
                             const int* __restrict__ neg_items,
                             const int* __restrict__ rowPtr, const int2* __restrict__ csr,
                             const u16* __restrict__ cur, float* __restrict__ sampled) {
    int gtid = blockIdx.x * blockDim.x + threadIdx.x;
    int slot = gtid >> 3;
    int t    = gtid & 7;
    if (slot >= NSAMP) return;
    int row;
    if (slot < BATCH)          row = users[slot];
    else if (slot < 2 * BATCH) row = pos_items[slot - BATCH] + NUM_USERS;
    else                       row = neg_items[slot - 2 * BATCH] + NUM_USERS;

    int beg = rowPtr[row], end = rowPtr[row + 1];
    float a[8];
    #pragma unroll
    for (int i = 0; i < 8; ++i) a[i] = 0.f;

    int e = beg;
    for (; e + 7 < end; e += 8) {
        int2 p[8];
        #pragma unroll
        for (int j = 0; j < 8; ++j) p[j] = csr[e + j];
        uint4 x[8];
        #pragma unroll
        for (int j = 0; j < 8; ++j)
            x[j] = *(const uint4*)(cur + ((long)p[j].x << 6) + (t << 3));
        #pragma unroll
        for (int j = 0; j < 8; ++j) {
            float v = __int_as_float(p[j].y);
            ACCX(v, x[j]);
        }
    }
    for (; e < end; ++e) {
        int2 p = csr[e];
        float v = __int_as_float(p.y);
        uint4 x = *(const uint4*)(cur + ((long)p.x << 6) + (t << 3));
        ACCX(v, x);
    }

    float4* dst = (float4*)(sampled + ((long)slot << 6) + (t << 3));
    dst[0] = make_float4(a[0], a[1], a[2], a[3]);
    dst[1] = make_float4(a[4], a[5], a[6], a[7]);
}

// One wave per batch element; lane = embedding dim.
// final = (emb + l1 + l2 + l3)/4 -> dot scaled by 1/16. l3 from sampled buf.
__global__ void score_kernel(const int* __restrict__ users,
                             const int* __restrict__ pos_items,
                             const int* __restrict__ neg_items,
                             const float* __restrict__ uemb,
                             const float* __restrict__ iemb,
                             const u16* __restrict__ l1,
                             const u16* __restrict__ l2,
                             const float* __restrict__ sampled,
                             float* __restrict__ out) {
    int gtid = blockIdx.x * blockDim.x + threadIdx.x;
    int wave = gtid >> 6;
    int lane = threadIdx.x & 63;
    if (wave >= BATCH) return;
    int u = users[wave];
    int p = pos_items[wave];
    int n = neg_items[wave];
    long U = (long)u * EMB + lane;
    long P = (long)(p + NUM_USERS) * EMB + lane;
    long N = (long)(n + NUM_USERS) * EMB + lane;
    float ue = uemb[(long)u * EMB + lane] + bf2f(l1[U]) + bf2f(l2[U])
             + sampled[(long)wave * EMB + lane];
    float pe = iemb[(long)p * EMB + lane] + bf2f(l1[P]) + bf2f(l2[P])
             + sampled[(long)(BATCH + wave) * EMB + lane];
    float ne = iemb[(long)n * EMB + lane] + bf2f(l1[N]) + bf2f(l2[N])
             + sampled[(long)(2 * BATCH + wave) * EMB + lane];
    float ps = ue * pe;
    float ns = ue * ne;
    #pragma unroll
    for (int off = 32; off > 0; off >>= 1) {
        ps += __shfl_down(ps, off, 64);
        ns += __shfl_down(ns, off, 64);
    }
    if (lane == 0) {
        out[wave]         = ps * 0.0625f;
        out[BATCH + wave] = ns * 0.0625f;
    }
}

extern "C" void kernel_launch(void* const* d_in, const int* in_sizes, int n_in,
                              void* d_out, int out_size, void* d_ws, size_t ws_size,
                              hipStream_t stream) {
    const int*   users = (const int*)d_in[0];
    const int*   pos   = (const int*)d_in[1];
    const int*   neg   = (const int*)d_in[2];
    const int*   rows  = (const int*)d_in[3];
    const int*   cols  = (const int*)d_in[4];
    const float* vals  = (const float*)d_in[5];
    const float* uemb  = (const float*)d_in[6];
    const float* iemb  = (const float*)d_in[7];
    float* out = (float*)d_out;

    const size_t tblElems = (size_t)NNODES * EMB;       // bf16 elems, 19.2 MB each
    u16*  B0      = (u16*)d_ws;                         // l0
    u16*  B1      = B0 + tblElems;                      // l1
    u16*  B2      = B1 + tblElems;                      // l2
    int2* csr     = (int2*)(B2 + tblElems);             // NEDGES int2 = 38.4 MB
    int*  rowPtr  = (int*)(csr + NEDGES);               // RP_ALLOC ints
    int*  cnt     = rowPtr + RP_ALLOC;                  // RP_ALLOC ints (zeroed)
    int*  fill    = cnt + RP_ALLOC;                     // RP_ALLOC ints (zeroed)
    int*  partials= fill + RP_ALLOC;                    // 256 ints
    float* sampled= (float*)(partials + 256);           // NSAMP*64 fp32 = 3.1 MB
    // total ~101 MB

    // zero cnt + fill in one memset (contiguous)
    (void)hipMemsetAsync(cnt, 0, (size_t)2 * RP_ALLOC * sizeof(int), stream);

    // init l0 (bf16) -- independent, issue first
    const long n4 = (long)tblElems / 4;
    init_kernel<<<(int)((n4 + 255) / 256), 256, 0, stream>>>(uemb, iemb, B0);

    // CSR build: hist -> 3-phase scan -> scatter
    hist_kernel<<<(NEDGES / 4 + 255) / 256, 256, 0, stream>>>(rows, cnt);
    chunkscan_kernel<<<NCHUNK, 1024, 0, stream>>>(cnt, rowPtr, partials);
    scanpart_kernel<<<1, 64, 0, stream>>>(partials);
    addback_kernel<<<NCHUNK, 1024, 0, stream>>>(rowPtr, partials);
    scatter_kernel<<<(NEDGES + 255) / 256, 256, 0, stream>>>(rows, cols, vals,
                                                             rowPtr, fill, csr);

    // layers 1,2 full; layer 3 only at sampled rows
    const long nth = (long)NNODES * 8;
    const int  spmmGrid = (int)((nth + 255) / 256);
    spmm_csr<<<spmmGrid, 256, 0, stream>>>(rowPtr, csr, B0, B1);
    spmm_csr<<<spmmGrid, 256, 0, stream>>>(rowPtr, csr, B1, B2);
    spmm_sampled<<<(NSAMP * 8 + 255) / 256, 256, 0, stream>>>(users, pos, neg,
                                                              rowPtr, csr, B2, sampled);

    score_kernel<<<(BATCH * 64) / 256, 256, 0, stream>>>(users, pos, neg,
                                                         uemb, iemb, B1, B2, sampled, out);
}

// Round 5
// 456.263 us; speedup vs baseline: 1.7335x; 1.7335x over previous
//
#include <hip/hip_runtime.h>

#define NUM_USERS 100000
#define NUM_ITEMS 50000
#define NNODES    150000
#define EMB       64
#define NEDGES    4800000
#define BATCH     4096
#define BUCKETS   293           // 512-row buckets (293*512 = 150016 >= NNODES)
#define BROWS     512
#define EPB       15360         // edges per binA block (30 rounds of 512)
#define NROUND    30
#define NBLK_A    313           // ceil(NEDGES/EPB)
#define CAP       17408         // per-bucket tmp capacity (mean 16382, +8 sigma)
#define NSAMP     (3 * BATCH)   // sampled rows for layer 3

typedef unsigned short u16;
typedef unsigned int   u32;
typedef unsigned long long u64;
typedef float f32x4 __attribute__((ext_vector_type(4)));

__device__ inline float bf2f(u16 u) { return __uint_as_float(((u32)u) << 16); }
__device__ inline u16 f2bf(float f) {                 // RNE
    u32 b = __float_as_uint(f);
    b += 0x7FFFu + ((b >> 16) & 1u);
    return (u16)(b >> 16);
}
__device__ inline u32 pack2(float a, float b) {
    return (u32)f2bf(a) | ((u32)f2bf(b) << 16);
}

// l0 init: concat(user_emb, item_emb) -> bf16 table. nt loads (read-once),
// cached stores (l0 is gathered immediately by spmm layer 1).
__global__ void init_kernel(const float* __restrict__ user_emb,
                            const float* __restrict__ item_emb,
                            u16* __restrict__ l0) {
    long i = (long)blockIdx.x * blockDim.x + threadIdx.x;   // float4 units
    const long n4 = (long)NNODES * EMB / 4;
    if (i >= n4) return;
    const long nu4 = (long)NUM_USERS * EMB / 4;
    f32x4 v;
    if (i < nu4) v = __builtin_nontemporal_load((const f32x4*)user_emb + i);
    else         v = __builtin_nontemporal_load((const f32x4*)item_emb + (i - nu4));
    ushort4 o;
    o.x = f2bf(v.x); o.y = f2bf(v.y); o.z = f2bf(v.z); o.w = f2bf(v.w);
    ((ushort4*)l0)[i] = o;
}

// --- Pass A: LDS hist (rows in regs) -> LDS scan -> parallel global
// reservations -> LDS bucket-sort -> per-wave burst flush (8B/lane).
// R4 lesson: bucket sort is mandatory -- direct random 8B scatter inflates
// WRITE 7.8x (partial lines evicted from L2 between touches).
// EPB=15360: 313 blocks (vs 586), slices avg 52 edges (~420B) -> fewer
// partial-line flush writes, half the scan/reservation overhead.
// LDS 127.6KB static -> 1 block/CU, 8 waves.
// pack.x = (rowLocal<<18) | col
__global__ void __launch_bounds__(512) binA_kernel(const int* __restrict__ rows,
                                                   const int* __restrict__ cols,
                                                   const float* __restrict__ vals,
                                                   int* __restrict__ bfill,
                                                   int2* __restrict__ tmp) {
    __shared__ int2 ebuf[EPB];                 // 120 KB bucket-sorted edges
    __shared__ int  hist[BUCKETS];
    __shared__ int  start[BUCKETS];
    __shared__ int  cursor[BUCKETS];
    __shared__ int  gbase[BUCKETS];
    const int tid = threadIdx.x;
    for (int i = tid; i < BUCKETS; i += 512) hist[i] = 0;
    __syncthreads();

    const long base = (long)blockIdx.x * EPB;
    int rsave[NROUND];                          // rows read ONCE, kept in regs
    #pragma unroll
    for (int k = 0; k < NROUND; ++k) {
        long e = base + (long)k * 512 + tid;
        int r = -1;
        if (e < NEDGES) {
            r = __builtin_nontemporal_load(rows + e);
            atomicAdd(&hist[r >> 9], 1);
        }
        rsave[k] = r;
    }
    __syncthreads();

    // exclusive scan hist -> start/cursor (wave 0, 64-chunks with carry)
    if (tid < 64) {
        int carry = 0;
        for (int cb = 0; cb < BUCKETS; cb += 64) {
            int i = cb + tid;
            int orig = (i < BUCKETS) ? hist[i] : 0;
            int x = orig;
            #pragma unroll
            for (int d = 1; d < 64; d <<= 1) {
                int t = __shfl_up(x, d, 64);
                if (tid >= d) x += t;
            }
            int total = __shfl(x, 63, 64);
            if (i < BUCKETS) { start[i] = x - orig + carry; cursor[i] = x - orig + carry; }
            carry += total;
        }
    }
    __syncthreads();

    // parallel global reservations (one atomic per non-empty bucket) --
    // latency hidden under the LDS scatter below
    for (int b = tid; b < BUCKETS; b += 512) {
        int h = hist[b];
        gbase[b] = h ? b * CAP + atomicAdd(&bfill[b], h) : 0;
    }

    // scatter edges into bucket-sorted LDS
    #pragma unroll
    for (int k = 0; k < NROUND; ++k) {
        int r = rsave[k];
        if (r >= 0) {
            long e = base + (long)k * 512 + tid;
            int pos = atomicAdd(&cursor[r >> 9], 1);
            int c = __builtin_nontemporal_load(cols + e);
            float v = __builtin_nontemporal_load(vals + e);
            ebuf[pos] = make_int2(((r & 511) << 18) | c, __float_as_int(v));
        }
    }
    __syncthreads();

    // burst flush: wave w copies whole slices as u64 (8 B/lane), plain stores
    const int wv = tid >> 6, lane = tid & 63;
    const u64* eb8 = (const u64*)ebuf;
    u64* gt8 = (u64*)tmp;
    for (int b = wv; b < BUCKETS; b += 8) {
        int cnt = hist[b];
        if (!cnt) continue;
        int  s = start[b];
        long d = (long)gbase[b];
        for (int i = lane; i < cnt; i += 64)
            gt8[d + i] = eb8[s + i];
    }
}

// Pass B: one block per bucket. Computes its own global base from bfill
// (1-block scan kernel removed), then LDS 512-row histogram + scan ->
// rowPtr, then scatter into the bucket's contiguous csr window
// (~131 KB, L2-dense -> write-combining works).
__global__ void __launch_bounds__(512) binB_kernel(const int* __restrict__ bfill,
                                                   const int2* __restrict__ tmp,
                                                   int* __restrict__ rowPtr,
                                                   int2* __restrict__ csr) {
    const int bucket = blockIdx.x;
    __shared__ int lhist[BROWS];
    __shared__ int rp[BROWS];
    __shared__ int fill[BROWS];
    const int t = threadIdx.x;
    lhist[t] = 0; fill[t] = 0;
    __syncthreads();

    const int cnt = bfill[bucket];
    const int2* src = tmp + (long)bucket * CAP;
    for (int k = t; k < cnt; k += 512)
        atomicAdd(&lhist[src[k].x >> 18], 1);
    __syncthreads();

    if (t < 64) {
        // global base: sum of bucket totals before this bucket (<=5 L2 loads/lane)
        int s = 0;
        for (int i = t; i < bucket; i += 64) s += bfill[i];
        #pragma unroll
        for (int off = 32; off > 0; off >>= 1) s += __shfl_down(s, off, 64);
        int gb = __shfl(s, 0, 64);

        int carry = 0;
        for (int cb = 0; cb < BROWS; cb += 64) {
            int i = cb + t;
            int orig = lhist[i];
            int x = orig;
            #pragma unroll
            for (int d = 1; d < 64; d <<= 1) {
                int tt = __shfl_up(x, d, 64);
                if (t >= d) x += tt;
            }
            int total = __shfl(x, 63, 64);
            rp[i] = x - orig + carry + gb;     // global exclusive offset
            carry += total;
        }
    }
    __syncthreads();

    int rowIdx = bucket * BROWS + t;           // max 150015; covers rowPtr[150000]
    rowPtr[rowIdx] = rp[t];

    for (int k = t; k < cnt; k += 512) {
        int2 p = src[k];
        int rL = p.x >> 18;
        int pos = rp[rL] + atomicAdd(&fill[rL], 1);
        csr[pos] = make_int2(p.x & 0x3FFFF, p.y);
    }
}

#define ACCX(V, X) { \
    a[0] += (V) * __uint_as_float((X).x << 16); \
    a[1] += (V) * __uint_as_float((X).x & 0xFFFF0000u); \
    a[2] += (V) * __uint_as_float((X).y << 16); \
    a[3] += (V) * __uint_as_float((X).y & 0xFFFF0000u); \
    a[4] += (V) * __uint_as_float((X).z << 16); \
    a[5] += (V) * __uint_as_float((X).z & 0xFFFF0000u); \
    a[6] += (V) * __uint_as_float((X).w << 16); \
    a[7] += (V) * __uint_as_float((X).w & 0xFFFF0000u); }

// --- SpMM: 8 lanes per row, each lane owns 8 bf16 dims (one uint4 gather).
// R0 form exactly: VGPR 44, no spill. spmm is random-gather byte-rate-bound
// (~3.3 TB/s effective); deeper pipelining spills and loses (R1/R2).
__global__ void spmm_csr(const int* __restrict__ rowPtr, const int2* __restrict__ csr,
                         const u16* __restrict__ cur, u16* __restrict__ nxt) {
    int gtid = blockIdx.x * blockDim.x + threadIdx.x;
    int row = gtid >> 3;
    int t   = gtid & 7;
    if (row >= NNODES) return;
    int beg = rowPtr[row], end = rowPtr[row + 1];
    float a[8];
    #pragma unroll
    for (int i = 0; i < 8; ++i) a[i] = 0.f;

    int e = beg;
    for (; e + 7 < end; e += 8) {            // 8 outstanding gathers
        int2 p[8];
        #pragma unroll
        for (int j = 0; j < 8; ++j) p[j] = csr[e + j];
        uint4 x[8];
        #pragma unroll
        for (int j = 0; j < 8; ++j)
            x[j] = *(const uint4*)(cur + ((long)p[j].x << 6) + (t << 3));
        #pragma unroll
        for (int j = 0; j < 8; ++j) {
            float v = __int_as_float(p[j].y);
            ACCX(v, x[j]);
        }
    }
    for (; e < end; ++e) {
        int2 p = csr[e];
        float v = __int_as_float(p.y);
        uint4 x = *(const uint4*)(cur + ((long)p.x << 6) + (t << 3));
        ACCX(v, x);
    }

    uint4 o;
    o.x = pack2(a[0], a[1]);
    o.y = pack2(a[2], a[3]);
    o.z = pack2(a[4], a[5]);
    o.w = pack2(a[6], a[7]);
    *(uint4*)(nxt + ((long)row << 6) + (t << 3)) = o;
}

// Layer 3 only at sampled rows: slot s<B -> users[s]; s<2B -> pos; s<3B -> neg.
// Output fp32 [NSAMP][64].
__global__ void spmm_sampled(const int* __restrict__ users,
                             const int* __restrict__ pos_items,
                             const int* __restrict__ neg_items,
                             const int* __restrict__ rowPtr, const int2* __restrict__ csr,
                             const u16* __restrict__ cur, float* __restrict__ sampled) {
    int gtid = blockIdx.x * blockDim.x + threadIdx.x;
    int slot = gtid >> 3;
    int t    = gtid & 7;
    if (slot >= NSAMP) return;
    int row;
    if (slot < BATCH)          row = users[slot];
    else if (slot < 2 * BATCH) row = pos_items[slot - BATCH] + NUM_USERS;
    else                       row = neg_items[slot - 2 * BATCH] + NUM_USERS;

    int beg = rowPtr[row], end = rowPtr[row + 1];
    float a[8];
    #pragma unroll
    for (int i = 0; i < 8; ++i) a[i] = 0.f;

    int e = beg;
    for (; e + 7 < end; e += 8) {
        int2 p[8];
        #pragma unroll
        for (int j = 0; j < 8; ++j) p[j] = csr[e + j];
        uint4 x[8];
        #pragma unroll
        for (int j = 0; j < 8; ++j)
            x[j] = *(const uint4*)(cur + ((long)p[j].x << 6) + (t << 3));
        #pragma unroll
        for (int j = 0; j < 8; ++j) {
            float v = __int_as_float(p[j].y);
            ACCX(v, x[j]);
        }
    }
    for (; e < end; ++e) {
        int2 p = csr[e];
        float v = __int_as_float(p.y);
        uint4 x = *(const uint4*)(cur + ((long)p.x << 6) + (t << 3));
        ACCX(v, x);
    }

    float4* dst = (float4*)(sampled + ((long)slot << 6) + (t << 3));
    dst[0] = make_float4(a[0], a[1], a[2], a[3]);
    dst[1] = make_float4(a[4], a[5], a[6], a[7]);
}

// One wave per batch element; lane = embedding dim.
// final = (emb + l1 + l2 + l3)/4 -> dot scaled by 1/16. l3 from sampled buf.
__global__ void score_kernel(const int* __restrict__ users,
                             const int* __restrict__ pos_items,
                             const int* __restrict__ neg_items,
                             const float* __restrict__ uemb,
                             const float* __restrict__ iemb,
                             const u16* __restrict__ l1,
                             const u16* __restrict__ l2,
                             const float* __restrict__ sampled,
                             float* __restrict__ out) {
    int gtid = blockIdx.x * blockDim.x + threadIdx.x;
    int wave = gtid >> 6;
    int lane = threadIdx.x & 63;
    if (wave >= BATCH) return;
    int u = users[wave];
    int p = pos_items[wave];
    int n = neg_items[wave];
    long U = (long)u * EMB + lane;
    long P = (long)(p + NUM_USERS) * EMB + lane;
    long N = (long)(n + NUM_USERS) * EMB + lane;
    float ue = uemb[(long)u * EMB + lane] + bf2f(l1[U]) + bf2f(l2[U])
             + sampled[(long)wave * EMB + lane];
    float pe = iemb[(long)p * EMB + lane] + bf2f(l1[P]) + bf2f(l2[P])
             + sampled[(long)(BATCH + wave) * EMB + lane];
    float ne = iemb[(long)n * EMB + lane] + bf2f(l1[N]) + bf2f(l2[N])
             + sampled[(long)(2 * BATCH + wave) * EMB + lane];
    float ps = ue * pe;
    float ns = ue * ne;
    #pragma unroll
    for (int off = 32; off > 0; off >>= 1) {
        ps += __shfl_down(ps, off, 64);
        ns += __shfl_down(ns, off, 64);
    }
    if (lane == 0) {
        out[wave]         = ps * 0.0625f;
        out[BATCH + wave] = ns * 0.0625f;
    }
}

extern "C" void kernel_launch(void* const* d_in, const int* in_sizes, int n_in,
                              void* d_out, int out_size, void* d_ws, size_t ws_size,
                              hipStream_t stream) {
    const int*   users = (const int*)d_in[0];
    const int*   pos   = (const int*)d_in[1];
    const int*   neg   = (const int*)d_in[2];
    const int*   rows  = (const int*)d_in[3];
    const int*   cols  = (const int*)d_in[4];
    const float* vals  = (const float*)d_in[5];
    const float* uemb  = (const float*)d_in[6];
    const float* iemb  = (const float*)d_in[7];
    float* out = (float*)d_out;

    const size_t tblElems = (size_t)NNODES * EMB;       // bf16 elems, 19.2 MB each
    u16*  B0      = (u16*)d_ws;                         // l0
    u16*  B1      = B0 + tblElems;                      // l1
    u16*  B2      = B1 + tblElems;                      // l2
    int2* tmp     = (int2*)(B2 + tblElems);             // BUCKETS*CAP int2 = 40.8 MB
    int2* csr     = (int2*)(tmp + (size_t)BUCKETS * CAP);   // NEDGES int2 = 38.4 MB
    int*  rowPtr  = (int*)(csr + NEDGES);               // 150016 ints
    int*  bfill   = rowPtr + 150016;                    // pad 320
    float* sampled= (float*)(bfill + 320);              // NSAMP*64 fp32 = 3.1 MB
    // total ~140 MB

    (void)hipMemsetAsync(bfill, 0, 320 * sizeof(int), stream);

    // init l0 (bf16)
    const long n4 = (long)tblElems / 4;
    init_kernel<<<(int)((n4 + 255) / 256), 256, 0, stream>>>(uemb, iemb, B0);

    // CSR build: LDS-sort + burst flush -> per-bucket resolve (scan inlined)
    binA_kernel<<<NBLK_A, 512, 0, stream>>>(rows, cols, vals, bfill, tmp);
    binB_kernel<<<BUCKETS, 512, 0, stream>>>(bfill, tmp, rowPtr, csr);

    // layers 1,2 full; layer 3 only at sampled rows
    const long nth = (long)NNODES * 8;
    const int  spmmGrid = (int)((nth + 255) / 256);
    spmm_csr<<<spmmGrid, 256, 0, stream>>>(rowPtr, csr, B0, B1);
    spmm_csr<<<spmmGrid, 256, 0, stream>>>(rowPtr, csr, B1, B2);
    spmm_sampled<<<(NSAMP * 8 + 255) / 256, 256, 0, stream>>>(users, pos, neg,
                                                              rowPtr, csr, B2, sampled);

    score_kernel<<<(BATCH * 64) / 256, 256, 0, stream>>>(users, pos, neg,
                                                         uemb, iemb, B1, B2, sampled, out);
}

// Round 6
// 426.145 us; speedup vs baseline: 1.8560x; 1.0707x over previous
//
#include <hip/hip_runtime.h>

#define NUM_USERS 100000
#define NUM_ITEMS 50000
#define NNODES    150000
#define EMB       64
#define NEDGES    4800000
#define BATCH     4096
#define BUCKETS   293           // 512-row buckets (293*512 = 150016 >= NNODES)
#define BROWS     512
#define EPB       9216          // edges per binA block (18 rounds of 512)
#define NROUND    18
#define NBLK_A    521           // ceil(NEDGES/EPB), 521*9216 = 4801536
#define CAP       17408         // per-bucket tmp capacity (mean 16382, +8 sigma)
#define NSTASH    17            // ceil(CAP/1024) -- binB per-thread stash slots
#define NSAMP     (3 * BATCH)   // sampled rows for layer 3

typedef unsigned short u16;
typedef unsigned int   u32;
typedef unsigned long long u64;
typedef float f32x4 __attribute__((ext_vector_type(4)));

__device__ inline float bf2f(u16 u) { return __uint_as_float(((u32)u) << 16); }
__device__ inline u16 f2bf(float f) {                 // RNE
    u32 b = __float_as_uint(f);
    b += 0x7FFFu + ((b >> 16) & 1u);
    return (u16)(b >> 16);
}
__device__ inline u32 pack2(float a, float b) {
    return (u32)f2bf(a) | ((u32)f2bf(b) << 16);
}

// l0 init: concat(user_emb, item_emb) -> bf16 table. nt loads (read-once),
// cached stores (l0 is gathered immediately by spmm layer 1).
__global__ void init_kernel(const float* __restrict__ user_emb,
                            const float* __restrict__ item_emb,
                            u16* __restrict__ l0) {
    long i = (long)blockIdx.x * blockDim.x + threadIdx.x;   // float4 units
    const long n4 = (long)NNODES * EMB / 4;
    if (i >= n4) return;
    const long nu4 = (long)NUM_USERS * EMB / 4;
    f32x4 v;
    if (i < nu4) v = __builtin_nontemporal_load((const f32x4*)user_emb + i);
    else         v = __builtin_nontemporal_load((const f32x4*)item_emb + (i - nu4));
    ushort4 o;
    o.x = f2bf(v.x); o.y = f2bf(v.y); o.z = f2bf(v.z); o.w = f2bf(v.w);
    ((ushort4*)l0)[i] = o;
}

// --- Pass A: LDS hist (rows in regs) -> LDS scan -> parallel global
// reservations -> LDS bucket-sort -> per-wave burst flush (8B/lane).
// R4 lesson: bucket sort mandatory (direct random 8B scatter = 7.8x write
// inflation). R5 lesson: slice size / block count don't matter -- build is
// latency-bound. EPB 9216: LDS 78.4KB -> 2 blocks/CU (4 waves/SIMD) with
// cross-block phase overlap.
// pack.x = (rowLocal<<18) | col
__global__ void __launch_bounds__(512) binA_kernel(const int* __restrict__ rows,
                                                   const int* __restrict__ cols,
                                                   const float* __restrict__ vals,
                                                   int* __restrict__ bfill,
                                                   int2* __restrict__ tmp) {
    __shared__ int2 ebuf[EPB];                 // 72 KB bucket-sorted edges
    __shared__ int  hist[BUCKETS];
    __shared__ int  start[BUCKETS];
    __shared__ int  cursor[BUCKETS];
    __shared__ int  gbase[BUCKETS];
    const int tid = threadIdx.x;
    for (int i = tid; i < BUCKETS; i += 512) hist[i] = 0;
    __syncthreads();

    const long base = (long)blockIdx.x * EPB;
    int rsave[NROUND];                          // rows read ONCE, kept in regs
    #pragma unroll
    for (int k = 0; k < NROUND; ++k) {
        long e = base + (long)k * 512 + tid;
        int r = -1;
        if (e < NEDGES) {
            r = __builtin_nontemporal_load(rows + e);
            atomicAdd(&hist[r >> 9], 1);
        }
        rsave[k] = r;
    }
    __syncthreads();

    // exclusive scan hist -> start/cursor (wave 0, 64-chunks with carry)
    if (tid < 64) {
        int carry = 0;
        for (int cb = 0; cb < BUCKETS; cb += 64) {
            int i = cb + tid;
            int orig = (i < BUCKETS) ? hist[i] : 0;
            int x = orig;
            #pragma unroll
            for (int d = 1; d < 64; d <<= 1) {
                int t = __shfl_up(x, d, 64);
                if (tid >= d) x += t;
            }
            int total = __shfl(x, 63, 64);
            if (i < BUCKETS) { start[i] = x - orig + carry; cursor[i] = x - orig + carry; }
            carry += total;
        }
    }
    __syncthreads();

    // parallel global reservations (one atomic per non-empty bucket) --
    // latency hidden under the LDS scatter below
    for (int b = tid; b < BUCKETS; b += 512) {
        int h = hist[b];
        gbase[b] = h ? b * CAP + atomicAdd(&bfill[b], h) : 0;
    }

    // scatter edges into bucket-sorted LDS
    #pragma unroll
    for (int k = 0; k < NROUND; ++k) {
        int r = rsave[k];
        if (r >= 0) {
            long e = base + (long)k * 512 + tid;
            int pos = atomicAdd(&cursor[r >> 9], 1);
            int c = __builtin_nontemporal_load(cols + e);
            float v = __builtin_nontemporal_load(vals + e);
            ebuf[pos] = make_int2(((r & 511) << 18) | c, __float_as_int(v));
        }
    }
    __syncthreads();

    // burst flush: wave w copies whole slices as u64 (8 B/lane), plain stores
    const int wv = tid >> 6, lane = tid & 63;
    const u64* eb8 = (const u64*)ebuf;
    u64* gt8 = (u64*)tmp;
    for (int b = wv; b < BUCKETS; b += 8) {
        int cnt = hist[b];
        if (!cnt) continue;
        int  s = start[b];
        long d = (long)gbase[b];
        for (int i = lane; i < cnt; i += 64)
            gt8[d + i] = eb8[s + i];
    }
}

// Pass B: one block per bucket, 1024 threads (4 waves/SIMD -- was 2).
// Bucket edges are stashed in registers via a fully-unrolled predicated
// 17-slot loop (compile-time indices -> no scratch), so tmp is read ONCE
// (nt loads). Then LDS 512-row hist + scan -> rowPtr, then scatter into the
// bucket's contiguous csr window (~131 KB, L2-dense -> write-combining).
__global__ void __launch_bounds__(1024) binB_kernel(const int* __restrict__ bfill,
                                                    const int2* __restrict__ tmp,
                                                    int* __restrict__ rowPtr,
                                                    int2* __restrict__ csr) {
    const int bucket = blockIdx.x;
    __shared__ int lhist[BROWS];
    __shared__ int rp[BROWS];
    __shared__ int fill[BROWS];
    const int t = threadIdx.x;
    if (t < BROWS) { lhist[t] = 0; fill[t] = 0; }
    __syncthreads();

    const int cnt = bfill[bucket];
    const u64* src8 = (const u64*)(tmp + (long)bucket * CAP);

    u64 stash[NSTASH];                         // edges kept in regs
    #pragma unroll
    for (int j = 0; j < NSTASH; ++j) {
        int k = t + (j << 10);
        if (k < cnt) {
            u64 raw = __builtin_nontemporal_load(src8 + k);
            stash[j] = raw;
            atomicAdd(&lhist[(int)(raw & 0xFFFFFFFFu) >> 18], 1);
        }
    }
    __syncthreads();

    if (t < 64) {
        // global base: sum of bucket totals before this bucket (<=5 L2 loads/lane)
        int s = 0;
        for (int i = t; i < bucket; i += 64) s += bfill[i];
        #pragma unroll
        for (int off = 32; off > 0; off >>= 1) s += __shfl_down(s, off, 64);
        int gb = __shfl(s, 0, 64);

        int carry = 0;
        for (int cb = 0; cb < BROWS; cb += 64) {
            int i = cb + t;
            int orig = lhist[i];
            int x = orig;
            #pragma unroll
            for (int d = 1; d < 64; d <<= 1) {
                int tt = __shfl_up(x, d, 64);
                if (t >= d) x += tt;
            }
            int total = __shfl(x, 63, 64);
            rp[i] = x - orig + carry + gb;     // global exclusive offset
            carry += total;
        }
    }
    __syncthreads();

    if (t < BROWS)
        rowPtr[bucket * BROWS + t] = rp[t];    // covers rowPtr[150000]

    #pragma unroll
    for (int j = 0; j < NSTASH; ++j) {
        int k = t + (j << 10);
        if (k < cnt) {
            u64 raw = stash[j];
            int px = (int)(raw & 0xFFFFFFFFu);
            int rL = px >> 18;
            int pos = rp[rL] + atomicAdd(&fill[rL], 1);
            csr[pos] = make_int2(px & 0x3FFFF, (int)(raw >> 32));
        }
    }
}

#define ACCX(V, X) { \
    a[0] += (V) * __uint_as_float((X).x << 16); \
    a[1] += (V) * __uint_as_float((X).x & 0xFFFF0000u); \
    a[2] += (V) * __uint_as_float((X).y << 16); \
    a[3] += (V) * __uint_as_float((X).y & 0xFFFF0000u); \
    a[4] += (V) * __uint_as_float((X).z << 16); \
    a[5] += (V) * __uint_as_float((X).z & 0xFFFF0000u); \
    a[6] += (V) * __uint_as_float((X).w << 16); \
    a[7] += (V) * __uint_as_float((X).w & 0xFFFF0000u); }

// --- SpMM: 8 lanes per row, each lane owns 8 bf16 dims (one uint4 gather).
// R0 form exactly: VGPR 44, no spill. spmm is random-gather request/byte
// rate bound (~3.3 TB/s L2-miss rate); deeper pipelining spills (R1/R2).
__global__ void spmm_csr(const int* __restrict__ rowPtr, const int2* __restrict__ csr,
                         const u16* __restrict__ cur, u16* __restrict__ nxt) {
    int gtid = blockIdx.x * blockDim.x + threadIdx.x;
    int row = gtid >> 3;
    int t   = gtid & 7;
    if (row >= NNODES) return;
    int beg = rowPtr[row], end = rowPtr[row + 1];
    float a[8];
    #pragma unroll
    for (int i = 0; i < 8; ++i) a[i] = 0.f;

    int e = beg;
    for (; e + 7 < end; e += 8) {            // 8 outstanding gathers
        int2 p[8];
        #pragma unroll
        for (int j = 0; j < 8; ++j) p[j] = csr[e + j];
        uint4 x[8];
        #pragma unroll
        for (int j = 0; j < 8; ++j)
            x[j] = *(const uint4*)(cur + ((long)p[j].x << 6) + (t << 3));
        #pragma unroll
        for (int j = 0; j < 8; ++j) {
            float v = __int_as_float(p[j].y);
            ACCX(v, x[j]);
        }
    }
    for (; e < end; ++e) {
        int2 p = csr[e];
        float v = __int_as_float(p.y);
        uint4 x = *(const uint4*)(cur + ((long)p.x << 6) + (t << 3));
        ACCX(v, x);
    }

    uint4 o;
    o.x = pack2(a[0], a[1]);
    o.y = pack2(a[2], a[3]);
    o.z = pack2(a[4], a[5]);
    o.w = pack2(a[6], a[7]);
    *(uint4*)(nxt + ((long)row << 6) + (t << 3)) = o;
}

// Layer 3 only at sampled rows: slot s<B -> users[s]; s<2B -> pos; s<3B -> neg.
// Output fp32 [NSAMP][64].
__global__ void spmm_sampled(const int* __restrict__ users,
                             const int* __restrict__ pos_items,
                             const int* __restrict__ neg_items,
                             const int* __restrict__ rowPtr, const int2* __restrict__ csr,
                             const u16* __restrict__ cur, float* __restrict__ sampled) {
    int gtid = blockIdx.x * blockDim.x + threadIdx.x;
    int slot = gtid >> 3;
    int t    = gtid & 7;
    if (slot >= NSAMP) return;
    int row;
    if (slot < BATCH)          row = users[slot];
    else if (slot < 2 * BATCH) row = pos_items[slot - BATCH] + NUM_USERS;
    else                       row = neg_items[slot - 2 * BATCH] + NUM_USERS;

    int beg = rowPtr[row], end = rowPtr[row + 1];
    float a[8];
    #pragma unroll
    for (int i = 0; i < 8; ++i) a[i] = 0.f;

    int e = beg;
    for (; e + 7 < end; e += 8) {
        int2 p[8];
        #pragma unroll
        for (int j = 0; j < 8; ++j) p[j] = csr[e + j];
        uint4 x[8];
        #pragma unroll
        for (int j = 0; j < 8; ++j)
            x[j] = *(const uint4*)(cur + ((long)p[j].x << 6) + (t << 3));
        #pragma unroll
        for (int j = 0; j < 8; ++j) {
            float v = __int_as_float(p[j].y);
            ACCX(v, x[j]);
        }
    }
    for (; e < end; ++e) {
        int2 p = csr[e];
        float v = __int_as_float(p.y);
        uint4 x = *(const uint4*)(cur + ((long)p.x << 6) + (t << 3));
        ACCX(v, x);
    }

    float4* dst = (float4*)(sampled + ((long)slot << 6) + (t << 3));
    dst[0] = make_float4(a[0], a[1], a[2], a[3]);
    dst[1] = make_float4(a[4], a[5], a[6], a[7]);
}

// One wave per batch element; lane = embedding dim.
// final = (emb + l1 + l2 + l3)/4 -> dot scaled by 1/16. l3 from sampled buf.
__global__ void score_kernel(const int* __restrict__ users,
                             const int* __restrict__ pos_items,
                             const int* __restrict__ neg_items,
                             const float* __restrict__ uemb,
                             const float* __restrict__ iemb,
                             const u16* __restrict__ l1,
                             const u16* __restrict__ l2,
                             const float* __restrict__ sampled,
                             float* __restrict__ out) {
    int gtid = blockIdx.x * blockDim.x + threadIdx.x;
    int wave = gtid >> 6;
    int lane = threadIdx.x & 63;
    if (wave >= BATCH) return;
    int u = users[wave];
    int p = pos_items[wave];
    int n = neg_items[wave];
    long U = (long)u * EMB + lane;
    long P = (long)(p + NUM_USERS) * EMB + lane;
    long N = (long)(n + NUM_USERS) * EMB + lane;
    float ue = uemb[(long)u * EMB + lane] + bf2f(l1[U]) + bf2f(l2[U])
             + sampled[(long)wave * EMB + lane];
    float pe = iemb[(long)p * EMB + lane] + bf2f(l1[P]) + bf2f(l2[P])
             + sampled[(long)(BATCH + wave) * EMB + lane];
    float ne = iemb[(long)n * EMB + lane] + bf2f(l1[N]) + bf2f(l2[N])
             + sampled[(long)(2 * BATCH + wave) * EMB + lane];
    float ps = ue * pe;
    float ns = ue * ne;
    #pragma unroll
    for (int off = 32; off > 0; off >>= 1) {
        ps += __shfl_down(ps, off, 64);
        ns += __shfl_down(ns, off, 64);
    }
    if (lane == 0) {
        out[wave]         = ps * 0.0625f;
        out[BATCH + wave] = ns * 0.0625f;
    }
}

extern "C" void kernel_launch(void* const* d_in, const int* in_sizes, int n_in,
                              void* d_out, int out_size, void* d_ws, size_t ws_size,
                              hipStream_t stream) {
    const int*   users = (const int*)d_in[0];
    const int*   pos   = (const int*)d_in[1];
    const int*   neg   = (const int*)d_in[2];
    const int*   rows  = (const int*)d_in[3];
    const int*   cols  = (const int*)d_in[4];
    const float* vals  = (const float*)d_in[5];
    const float* uemb  = (const float*)d_in[6];
    const float* iemb  = (const float*)d_in[7];
    float* out = (float*)d_out;

    const size_t tblElems = (size_t)NNODES * EMB;       // bf16 elems, 19.2 MB each
    u16*  B0      = (u16*)d_ws;                         // l0
    u16*  B1      = B0 + tblElems;                      // l1
    u16*  B2      = B1 + tblElems;                      // l2
    int2* tmp     = (int2*)(B2 + tblElems);             // BUCKETS*CAP int2 = 40.8 MB
    int2* csr     = (int2*)(tmp + (size_t)BUCKETS * CAP);   // NEDGES int2 = 38.4 MB
    int*  rowPtr  = (int*)(csr + NEDGES);               // 150016 ints
    int*  bfill   = rowPtr + 150016;                    // pad 320
    float* sampled= (float*)(bfill + 320);              // NSAMP*64 fp32 = 3.1 MB
    // total ~140 MB

    (void)hipMemsetAsync(bfill, 0, 320 * sizeof(int), stream);

    // init l0 (bf16)
    const long n4 = (long)tblElems / 4;
    init_kernel<<<(int)((n4 + 255) / 256), 256, 0, stream>>>(uemb, iemb, B0);

    // CSR build: LDS-sort + burst flush -> per-bucket resolve (reg-stashed)
    binA_kernel<<<NBLK_A, 512, 0, stream>>>(rows, cols, vals, bfill, tmp);
    binB_kernel<<<BUCKETS, 1024, 0, stream>>>(bfill, tmp, rowPtr, csr);

    // layers 1,2 full; layer 3 only at sampled rows
    const long nth = (long)NNODES * 8;
    const int  spmmGrid = (int)((nth + 255) / 256);
    spmm_csr<<<spmmGrid, 256, 0, stream>>>(rowPtr, csr, B0, B1);
    spmm_csr<<<spmmGrid, 256, 0, stream>>>(rowPtr, csr, B1, B2);
    spmm_sampled<<<(NSAMP * 8 + 255) / 256, 256, 0, stream>>>(users, pos, neg,
                                                              rowPtr, csr, B2, sampled);

    score_kernel<<<(BATCH * 64) / 256, 256, 0, stream>>>(users, pos, neg,
                                                         uemb, iemb, B1, B2, sampled, out);
}

// Round 7
// 409.063 us; speedup vs baseline: 1.9335x; 1.0418x over previous
//
#include <hip/hip_runtime.h>

#define NUM_USERS 100000
#define NUM_ITEMS 50000
#define NNODES    150000
#define EMB       64
#define NEDGES    4800000
#define BATCH     4096
#define BUCKETS   293           // 512-row buckets (293*512 = 150016 >= NNODES)
#define BROWS     512
#define EPB       9216          // edges per binA block (18 rounds of 512)
#define NROUND    18
#define NBLK_A    521           // ceil(NEDGES/EPB), 521*9216 = 4801536
#define CAP       17408         // per-bucket tmp capacity (mean 16382, +8 sigma)
#define NSTASH    17            // ceil(CAP/1024) -- binB per-thread stash slots
#define NSAMP     (3 * BATCH)   // sampled rows for layer 3

typedef unsigned short u16;
typedef unsigned int   u32;
typedef unsigned long long u64;
typedef float f32x4 __attribute__((ext_vector_type(4)));

__device__ inline float bf2f(u16 u) { return __uint_as_float(((u32)u) << 16); }
__device__ inline u16 f2bf(float f) {                 // RNE
    u32 b = __float_as_uint(f);
    b += 0x7FFFu + ((b >> 16) & 1u);
    return (u16)(b >> 16);
}
__device__ inline u32 pack2(float a, float b) {
    return (u32)f2bf(a) | ((u32)f2bf(b) << 16);
}

// l0 init: concat(user_emb, item_emb) -> bf16 table. nt loads (read-once),
// cached stores (l0 is gathered immediately by spmm layer 1).
__global__ void init_kernel(const float* __restrict__ user_emb,
                            const float* __restrict__ item_emb,
                            u16* __restrict__ l0) {
    long i = (long)blockIdx.x * blockDim.x + threadIdx.x;   // float4 units
    const long n4 = (long)NNODES * EMB / 4;
    if (i >= n4) return;
    const long nu4 = (long)NUM_USERS * EMB / 4;
    f32x4 v;
    if (i < nu4) v = __builtin_nontemporal_load((const f32x4*)user_emb + i);
    else         v = __builtin_nontemporal_load((const f32x4*)item_emb + (i - nu4));
    ushort4 o;
    o.x = f2bf(v.x); o.y = f2bf(v.y); o.z = f2bf(v.z); o.w = f2bf(v.w);
    ((ushort4*)l0)[i] = o;
}

// --- Pass A: LDS hist (rows in regs) -> LDS scan -> parallel global
// reservations -> LDS bucket-sort -> per-wave burst flush (8B/lane).
// R4 lesson: bucket sort mandatory (direct random 8B scatter = 7.8x write
// inflation). R6: EPB 9216 -> LDS 78.4KB -> 2 blocks/CU (4 waves/SIMD).
// pack.x = (rowLocal<<18) | col
__global__ void __launch_bounds__(512) binA_kernel(const int* __restrict__ rows,
                                                   const int* __restrict__ cols,
                                                   const float* __restrict__ vals,
                                                   int* __restrict__ bfill,
                                                   int2* __restrict__ tmp) {
    __shared__ int2 ebuf[EPB];                 // 72 KB bucket-sorted edges
    __shared__ int  hist[BUCKETS];
    __shared__ int  start[BUCKETS];
    __shared__ int  cursor[BUCKETS];
    __shared__ int  gbase[BUCKETS];
    const int tid = threadIdx.x;
    for (int i = tid; i < BUCKETS; i += 512) hist[i] = 0;
    __syncthreads();

    const long base = (long)blockIdx.x * EPB;
    int rsave[NROUND];                          // rows read ONCE, kept in regs
    #pragma unroll
    for (int k = 0; k < NROUND; ++k) {
        long e = base + (long)k * 512 + tid;
        int r = -1;
        if (e < NEDGES) {
            r = __builtin_nontemporal_load(rows + e);
            atomicAdd(&hist[r >> 9], 1);
        }
        rsave[k] = r;
    }
    __syncthreads();

    // exclusive scan hist -> start/cursor (wave 0, 64-chunks with carry)
    if (tid < 64) {
        int carry = 0;
        for (int cb = 0; cb < BUCKETS; cb += 64) {
            int i = cb + tid;
            int orig = (i < BUCKETS) ? hist[i] : 0;
            int x = orig;
            #pragma unroll
            for (int d = 1; d < 64; d <<= 1) {
                int t = __shfl_up(x, d, 64);
                if (tid >= d) x += t;
            }
            int total = __shfl(x, 63, 64);
            if (i < BUCKETS) { start[i] = x - orig + carry; cursor[i] = x - orig + carry; }
            carry += total;
        }
    }
    __syncthreads();

    // parallel global reservations (one atomic per non-empty bucket) --
    // latency hidden under the LDS scatter below
    for (int b = tid; b < BUCKETS; b += 512) {
        int h = hist[b];
        gbase[b] = h ? b * CAP + atomicAdd(&bfill[b], h) : 0;
    }

    // scatter edges into bucket-sorted LDS
    #pragma unroll
    for (int k = 0; k < NROUND; ++k) {
        int r = rsave[k];
        if (r >= 0) {
            long e = base + (long)k * 512 + tid;
            int pos = atomicAdd(&cursor[r >> 9], 1);
            int c = __builtin_nontemporal_load(cols + e);
            float v = __builtin_nontemporal_load(vals + e);
            ebuf[pos] = make_int2(((r & 511) << 18) | c, __float_as_int(v));
        }
    }
    __syncthreads();

    // burst flush: wave w copies whole slices as u64 (8 B/lane), plain stores
    const int wv = tid >> 6, lane = tid & 63;
    const u64* eb8 = (const u64*)ebuf;
    u64* gt8 = (u64*)tmp;
    for (int b = wv; b < BUCKETS; b += 8) {
        int cnt = hist[b];
        if (!cnt) continue;
        int  s = start[b];
        long d = (long)gbase[b];
        for (int i = lane; i < cnt; i += 64)
            gt8[d + i] = eb8[s + i];
    }
}

// Pass B: one block per bucket, 1024 threads (4 waves/SIMD). Bucket edges
// stashed in registers (fully-unrolled 17-slot predicated loop, compile-time
// indices -> no scratch) so tmp is read ONCE (nt). Then LDS 512-row hist +
// scan -> rowPtr, then scatter into the bucket's contiguous csr window.
__global__ void __launch_bounds__(1024) binB_kernel(const int* __restrict__ bfill,
                                                    const int2* __restrict__ tmp,
                                                    int* __restrict__ rowPtr,
                                                    int2* __restrict__ csr) {
    const int bucket = blockIdx.x;
    __shared__ int lhist[BROWS];
    __shared__ int rp[BROWS];
    __shared__ int fill[BROWS];
    const int t = threadIdx.x;
    if (t < BROWS) { lhist[t] = 0; fill[t] = 0; }
    __syncthreads();

    const int cnt = bfill[bucket];
    const u64* src8 = (const u64*)(tmp + (long)bucket * CAP);

    u64 stash[NSTASH];                         // edges kept in regs
    #pragma unroll
    for (int j = 0; j < NSTASH; ++j) {
        int k = t + (j << 10);
        if (k < cnt) {
            u64 raw = __builtin_nontemporal_load(src8 + k);
            stash[j] = raw;
            atomicAdd(&lhist[(int)(raw & 0xFFFFFFFFu) >> 18], 1);
        }
    }
    __syncthreads();

    if (t < 64) {
        // global base: sum of bucket totals before this bucket (<=5 L2 loads/lane)
        int s = 0;
        for (int i = t; i < bucket; i += 64) s += bfill[i];
        #pragma unroll
        for (int off = 32; off > 0; off >>= 1) s += __shfl_down(s, off, 64);
        int gb = __shfl(s, 0, 64);

        int carry = 0;
        for (int cb = 0; cb < BROWS; cb += 64) {
            int i = cb + t;
            int orig = lhist[i];
            int x = orig;
            #pragma unroll
            for (int d = 1; d < 64; d <<= 1) {
                int tt = __shfl_up(x, d, 64);
                if (t >= d) x += tt;
            }
            int total = __shfl(x, 63, 64);
            rp[i] = x - orig + carry + gb;     // global exclusive offset
            carry += total;
        }
    }
    __syncthreads();

    if (t < BROWS)
        rowPtr[bucket * BROWS + t] = rp[t];    // covers rowPtr[150000]

    #pragma unroll
    for (int j = 0; j < NSTASH; ++j) {
        int k = t + (j << 10);
        if (k < cnt) {
            u64 raw = stash[j];
            int px = (int)(raw & 0xFFFFFFFFu);
            int rL = px >> 18;
            int pos = rp[rL] + atomicAdd(&fill[rL], 1);
            csr[pos] = make_int2(px & 0x3FFFF, (int)(raw >> 32));
        }
    }
}

#define ACCX(V, X) { \
    a[0] += (V) * __uint_as_float((X).x << 16); \
    a[1] += (V) * __uint_as_float((X).x & 0xFFFF0000u); \
    a[2] += (V) * __uint_as_float((X).y << 16); \
    a[3] += (V) * __uint_as_float((X).y & 0xFFFF0000u); \
    a[4] += (V) * __uint_as_float((X).z << 16); \
    a[5] += (V) * __uint_as_float((X).z & 0xFFFF0000u); \
    a[6] += (V) * __uint_as_float((X).w << 16); \
    a[7] += (V) * __uint_as_float((X).w & 0xFFFF0000u); }

// --- SpMM: 8 lanes per row, each lane owns 8 bf16 dims (one uint4 gather).
// R7 experiment: prefetch ONLY the next group's csr p-block (+16 VGPR,
// no launch_bounds -- R1/R2's spills came from over-constrained allocator).
// Removes the p-load from the serial chain p -> addr -> gather -> FMA.
// Spill tripwire: WRITE_SIZE must stay 18.75 MB.
__device__ __forceinline__ void row_accum(int beg, int end, int t,
                                          const int2* __restrict__ csr,
                                          const u16* __restrict__ cur,
                                          float* __restrict__ a) {
    int nfull = (end - beg) >> 3;
    int e = beg;
    if (nfull > 0) {
        int2 pC[8];
        #pragma unroll
        for (int j = 0; j < 8; ++j) pC[j] = csr[e + j];
        for (int g = 1; g < nfull; ++g) {
            int2 pN[8];                        // prefetch next group's p
            #pragma unroll
            for (int j = 0; j < 8; ++j) pN[j] = csr[e + 8 + j];
            uint4 x[8];
            #pragma unroll
            for (int j = 0; j < 8; ++j)
                x[j] = *(const uint4*)(cur + ((long)pC[j].x << 6) + (t << 3));
            #pragma unroll
            for (int j = 0; j < 8; ++j) {
                float v = __int_as_float(pC[j].y);
                ACCX(v, x[j]);
            }
            #pragma unroll
            for (int j = 0; j < 8; ++j) pC[j] = pN[j];
            e += 8;
        }
        uint4 x[8];
        #pragma unroll
        for (int j = 0; j < 8; ++j)
            x[j] = *(const uint4*)(cur + ((long)pC[j].x << 6) + (t << 3));
        #pragma unroll
        for (int j = 0; j < 8; ++j) {
            float v = __int_as_float(pC[j].y);
            ACCX(v, x[j]);
        }
        e += 8;
    }
    for (; e < end; ++e) {                     // serial tail (<=7 edges)
        int2 p = csr[e];
        float v = __int_as_float(p.y);
        uint4 x = *(const uint4*)(cur + ((long)p.x << 6) + (t << 3));
        ACCX(v, x);
    }
}

__global__ void spmm_csr(const int* __restrict__ rowPtr, const int2* __restrict__ csr,
                         const u16* __restrict__ cur, u16* __restrict__ nxt) {
    int gtid = blockIdx.x * blockDim.x + threadIdx.x;
    int row = gtid >> 3;
    int t   = gtid & 7;
    if (row >= NNODES) return;
    int beg = rowPtr[row], end = rowPtr[row + 1];
    float a[8];
    #pragma unroll
    for (int i = 0; i < 8; ++i) a[i] = 0.f;

    row_accum(beg, end, t, csr, cur, a);

    uint4 o;
    o.x = pack2(a[0], a[1]);
    o.y = pack2(a[2], a[3]);
    o.z = pack2(a[4], a[5]);
    o.w = pack2(a[6], a[7]);
    *(uint4*)(nxt + ((long)row << 6) + (t << 3)) = o;
}

// Layer 3 only at sampled rows: slot s<B -> users[s]; s<2B -> pos; s<3B -> neg.
// Output fp32 [NSAMP][64].
__global__ void spmm_sampled(const int* __restrict__ users,
                             const int* __restrict__ pos_items,
                             const int* __restrict__ neg_items,
                             const int* __restrict__ rowPtr, const int2* __restrict__ csr,
                             const u16* __restrict__ cur, float* __restrict__ sampled) {
    int gtid = blockIdx.x * blockDim.x + threadIdx.x;
    int slot = gtid >> 3;
    int t    = gtid & 7;
    if (slot >= NSAMP) return;
    int row;
    if (slot < BATCH)          row = users[slot];
    else if (slot < 2 * BATCH) row = pos_items[slot - BATCH] + NUM_USERS;
    else                       row = neg_items[slot - 2 * BATCH] + NUM_USERS;

    int beg = rowPtr[row], end = rowPtr[row + 1];
    float a[8];
    #pragma unroll
    for (int i = 0; i < 8; ++i) a[i] = 0.f;

    row_accum(beg, end, t, csr, cur, a);

    float4* dst = (float4*)(sampled + ((long)slot << 6) + (t << 3));
    dst[0] = make_float4(a[0], a[1], a[2], a[3]);
    dst[1] = make_float4(a[4], a[5], a[6], a[7]);
}

// One wave per batch element; lane = embedding dim.
// final = (emb + l1 + l2 + l3)/4 -> dot scaled by 1/16. l3 from sampled buf.
__global__ void score_kernel(const int* __restrict__ users,
                             const int* __restrict__ pos_items,
                             const int* __restrict__ neg_items,
                             const float* __restrict__ uemb,
                             const float* __restrict__ iemb,
                             const u16* __restrict__ l1,
                             const u16* __restrict__ l2,
                             const float* __restrict__ sampled,
                             float* __restrict__ out) {
    int gtid = blockIdx.x * blockDim.x + threadIdx.x;
    int wave = gtid >> 6;
    int lane = threadIdx.x & 63;
    if (wave >= BATCH) return;
    int u = users[wave];
    int p = pos_items[wave];
    int n = neg_items[wave];
    long U = (long)u * EMB + lane;
    long P = (long)(p + NUM_USERS) * EMB + lane;
    long N = (long)(n + NUM_USERS) * EMB + lane;
    float ue = uemb[(long)u * EMB + lane] + bf2f(l1[U]) + bf2f(l2[U])
             + sampled[(long)wave * EMB + lane];
    float pe = iemb[(long)p * EMB + lane] + bf2f(l1[P]) + bf2f(l2[P])
             + sampled[(long)(BATCH + wave) * EMB + lane];
    float ne = iemb[(long)n * EMB + lane] + bf2f(l1[N]) + bf2f(l2[N])
             + sampled[(long)(2 * BATCH + wave) * EMB + lane];
    float ps = ue * pe;
    float ns = ue * ne;
    #pragma unroll
    for (int off = 32; off > 0; off >>= 1) {
        ps += __shfl_down(ps, off, 64);
        ns += __shfl_down(ns, off, 64);
    }
    if (lane == 0) {
        out[wave]         = ps * 0.0625f;
        out[BATCH + wave] = ns * 0.0625f;
    }
}

extern "C" void kernel_launch(void* const* d_in, const int* in_sizes, int n_in,
                              void* d_out, int out_size, void* d_ws, size_t ws_size,
                              hipStream_t stream) {
    const int*   users = (const int*)d_in[0];
    const int*   pos   = (const int*)d_in[1];
    const int*   neg   = (const int*)d_in[2];
    const int*   rows  = (const int*)d_in[3];
    const int*   cols  = (const int*)d_in[4];
    const float* vals  = (const float*)d_in[5];
    const float* uemb  = (const float*)d_in[6];
    const float* iemb  = (const float*)d_in[7];
    float* out = (float*)d_out;

    const size_t tblElems = (size_t)NNODES * EMB;       // bf16 elems, 19.2 MB each
    u16*  B0      = (u16*)d_ws;                         // l0
    u16*  B1      = B0 + tblElems;                      // l1
    u16*  B2      = B1 + tblElems;                      // l2
    int2* tmp     = (int2*)(B2 + tblElems);             // BUCKETS*CAP int2 = 40.8 MB
    int2* csr     = (int2*)(tmp + (size_t)BUCKETS * CAP);   // NEDGES int2 = 38.4 MB
    int*  rowPtr  = (int*)(csr + NEDGES);               // 150016 ints
    int*  bfill   = rowPtr + 150016;                    // pad 320
    float* sampled= (float*)(bfill + 320);              // NSAMP*64 fp32 = 3.1 MB
    // total ~140 MB

    (void)hipMemsetAsync(bfill, 0, 320 * sizeof(int), stream);

    // init l0 (bf16)
    const long n4 = (long)tblElems / 4;
    init_kernel<<<(int)((n4 + 255) / 256), 256, 0, stream>>>(uemb, iemb, B0);

    // CSR build: LDS-sort + burst flush -> per-bucket resolve (reg-stashed)
    binA_kernel<<<NBLK_A, 512, 0, stream>>>(rows, cols, vals, bfill, tmp);
    binB_kernel<<<BUCKETS, 1024, 0, stream>>>(bfill, tmp, rowPtr, csr);

    // layers 1,2 full; layer 3 only at sampled rows
    const long nth = (long)NNODES * 8;
    const int  spmmGrid = (int)((nth + 255) / 256);
    spmm_csr<<<spmmGrid, 256, 0, stream>>>(rowPtr, csr, B0, B1);
    spmm_csr<<<spmmGrid, 256, 0, stream>>>(rowPtr, csr, B1, B2);
    spmm_sampled<<<(NSAMP * 8 + 255) / 256, 256, 0, stream>>>(users, pos, neg,
                                                              rowPtr, csr, B2, sampled);

    score_kernel<<<(BATCH * 64) / 256, 256, 0, stream>>>(users, pos, neg,
                                                         uemb, iemb, B1, B2, sampled, out);
}